// Round 7
// baseline (399.601 us; speedup 1.0000x reference)
//
#include <hip/hip_runtime.h>
#include <math.h>

typedef _Float16 f16x8 __attribute__((ext_vector_type(8)));
typedef _Float16 f16x4 __attribute__((ext_vector_type(4)));
typedef float f32x4 __attribute__((ext_vector_type(4)));

__device__ __forceinline__ void async_copy16(const void* g, void* l) {
    __builtin_amdgcn_global_load_lds(
        (const __attribute__((address_space(1))) void*)g,
        (__attribute__((address_space(3))) void*)l, 16, 0, 0);
}

// ---------------- fused prep: cast x->f16 | build W0t | build W1t ----------------
// (unchanged from R6 - passed)
__global__ __launch_bounds__(256) void prep_kernel(
    const float* __restrict__ x, _Float16* __restrict__ xh,
    const float* __restrict__ c0a, const float* __restrict__ c0b,
    const float* __restrict__ c0c, _Float16* __restrict__ W0t,
    const float* __restrict__ c1a, const float* __restrict__ c1b,
    const float* __restrict__ c1c, _Float16* __restrict__ W1t) {
    __shared__ float G[16384];
    const int b = blockIdx.x, t = threadIdx.x;
    if (b < 1024) {
        const float4* in4 = (const float4*)x;
        f16x4* out4 = (f16x4*)xh;
        const int base = b * 2048 + t;
#pragma unroll
        for (int u = 0; u < 8; ++u) {
            float4 v = in4[base + u * 256];
            f16x4 o;
            o[0] = (_Float16)v.x; o[1] = (_Float16)v.y;
            o[2] = (_Float16)v.z; o[3] = (_Float16)v.w;
            out4[base + u * 256] = o;
        }
    } else if (b < 1280) {
        const int o = (b - 1024) >> 4, p = (b - 1024) & 15;
        // G[q16][r8][j16][k8] = sum_ss c0b[r,j,p,ss]*c0c[ss,k,q]; idx=q*1024+rj*8+k
        {
            const int h = t >> 7, qk = t & 127, q = qk >> 3, k = qk & 7;
            float cr[8];
#pragma unroll
            for (int ss = 0; ss < 8; ++ss) cr[ss] = c0c[(ss * 8 + k) * 16 + q];
            for (int rj = h * 64; rj < h * 64 + 64; ++rj) {
                const float4* b4 = (const float4*)(c0b + (rj * 16 + p) * 8);
                float4 b0 = b4[0], b1 = b4[1];
                float s = b0.x * cr[0] + b0.y * cr[1] + b0.z * cr[2] + b0.w * cr[3]
                        + b1.x * cr[4] + b1.y * cr[5] + b1.z * cr[6] + b1.w * cr[7];
                G[q * 1024 + rj * 8 + k] = s;
            }
        }
        __syncthreads();
        const int i = t >> 5, j = (t >> 1) & 15, kq = t & 1;
        float a[8];
#pragma unroll
        for (int r = 0; r < 8; ++r) a[r] = c0a[(i * 16 + o) * 8 + r];
        const float4* G4 = (const float4*)G;
#pragma unroll
        for (int q = 0; q < 16; ++q) {
            float4 acc = {0.f, 0.f, 0.f, 0.f};
#pragma unroll
            for (int r = 0; r < 8; ++r) {
                float4 g = G4[q * 256 + r * 32 + j * 2 + kq];
                acc.x += a[r] * g.x; acc.y += a[r] * g.y;
                acc.z += a[r] * g.z; acc.w += a[r] * g.w;
            }
            f16x4 h4;
            h4[0] = (_Float16)acc.x; h4[1] = (_Float16)acc.y;
            h4[2] = (_Float16)acc.z; h4[3] = (_Float16)acc.w;
            *(f16x4*)(W0t + (size_t)((o * 16 + p) * 16 + q) * 1024 + t * 4) = h4;
        }
    } else {
        const int o = (b - 1280) >> 4, p = (b - 1280) & 15;
        // G[q8][r8][j16][k16] = sum_ss c1b[r,j,p,ss]*c1c[ss,k,q]; idx=q*2048+rj*16+k
        {
            const int h = t >> 7, qk = t & 127, q = qk >> 4, k = qk & 15;
            float cr[8];
#pragma unroll
            for (int ss = 0; ss < 8; ++ss) cr[ss] = c1c[(ss * 16 + k) * 8 + q];
            for (int rj = h * 64; rj < h * 64 + 64; ++rj) {
                const float4* b4 = (const float4*)(c1b + (rj * 16 + p) * 8);
                float4 b0 = b4[0], b1 = b4[1];
                float s = b0.x * cr[0] + b0.y * cr[1] + b0.z * cr[2] + b0.w * cr[3]
                        + b1.x * cr[4] + b1.y * cr[5] + b1.z * cr[6] + b1.w * cr[7];
                G[q * 2048 + rj * 16 + k] = s;
            }
        }
        __syncthreads();
        const int ig = t >> 6, j = (t >> 2) & 15, kq = t & 3;
        float a[4][8];
#pragma unroll
        for (int ii = 0; ii < 4; ++ii)
#pragma unroll
            for (int r = 0; r < 8; ++r) a[ii][r] = c1a[((ig * 4 + ii) * 8 + o) * 8 + r];
        const float4* G4 = (const float4*)G;
#pragma unroll
        for (int q = 0; q < 8; ++q) {
            float4 acc[4] = {{0,0,0,0},{0,0,0,0},{0,0,0,0},{0,0,0,0}};
#pragma unroll
            for (int r = 0; r < 8; ++r) {
                float4 g = G4[q * 512 + r * 64 + j * 4 + kq];
#pragma unroll
                for (int ii = 0; ii < 4; ++ii) {
                    acc[ii].x += a[ii][r] * g.x; acc[ii].y += a[ii][r] * g.y;
                    acc[ii].z += a[ii][r] * g.z; acc[ii].w += a[ii][r] * g.w;
                }
            }
            const size_t rowbase = (size_t)((o * 16 + p) * 8 + q) * 4096;
#pragma unroll
            for (int ii = 0; ii < 4; ++ii) {
                f16x4 h4;
                h4[0] = (_Float16)acc[ii].x; h4[1] = (_Float16)acc[ii].y;
                h4[2] = (_Float16)acc[ii].z; h4[3] = (_Float16)acc[ii].w;
                *(f16x4*)(W1t + rowbase + (ig * 4 + ii) * 256 + j * 16 + kq * 4) = h4;
            }
        }
    }
}

// -------- m97-clone GEMM: 128x128 tile, BK=64, 16x16x32 MFMA, classic 2-barrier --------
// C = A(MxK) * Bt(NxK)^T. 256 thr = 4 waves (2m x 2n), per-wave 64x64 = 4x4
// frags of 16x16. Per K-step per wave: 16 ds_read_b128 + 32 MFMA; staging
// 8 global_load_lds (width 16). NO manual waitcnt: compiler inserts precise
// lgkmcnt for ds_read->MFMA and the barrier drain (m97-verified structure,
// 874-912 TF / 36-37% MfmaUtil at 4096^3).
// LDS chunk-major (R1-R6: 0 bank conflicts): elem = ch*(128*8) + row*8,
//   ch = k/8 (8 chunks over BK=64). Staging thread t, load u: slot s=t+256u,
//   row = t&127 (u-invariant), ch = (t>>7)+2u => global k advance u*16 elems.
// Frag reads (16-lane groups read 256B contiguous -> conflict-free):
//   A frag i, k-half h: lane l -> row wm+i*16+(l&15), ch = h*4+(l>>4).
// MFMA 16x16x32_f16 mappings: A/B lane l holds row/col l&15, k=(l>>4)*8+j;
//   C/D col=lane&15, row=(lane>>4)*4+reg  [verified m89/m91].
// OUTMODE 1: f16 C = gelu(acc+bias);  OUTMODE 0: fp32 C = acc+bias
template <int OUTMODE>
__global__ __launch_bounds__(256) void gemm16(
    const _Float16* __restrict__ A, const _Float16* __restrict__ Bt,
    const float* __restrict__ bias, void* __restrict__ Cout,
    int M, int N, int K) {
    __shared__ alignas(16) _Float16 sA[128 * 64];
    __shared__ alignas(16) _Float16 sB[128 * 64];

    const int t = threadIdx.x, lane = t & 63, w = t >> 6;
    const int m0 = blockIdx.x * 128, n0 = blockIdx.y * 128;
    const int wm = (w & 1) * 64, wn = (w >> 1) * 64;
    const int l15 = lane & 15, lg = lane >> 4;

    f32x4 acc[4][4] = {};

    const _Float16* gA = A + (size_t)(m0 + (t & 127)) * K + (t >> 7) * 8;
    const _Float16* gB = Bt + (size_t)(n0 + (t & 127)) * K + (t >> 7) * 8;
    _Float16* lA = sA + t * 8;
    _Float16* lB = sB + t * 8;

    for (int k0 = 0; k0 < K; k0 += 64) {
#pragma unroll
        for (int u = 0; u < 4; ++u) {
            async_copy16(gA + k0 + u * 16, lA + u * 2048);
            async_copy16(gB + k0 + u * 16, lB + u * 2048);
        }
        __syncthreads();
#pragma unroll
        for (int h = 0; h < 2; ++h) {
            const int ch = h * 4 + lg;
            f16x8 af[4], bf[4];
#pragma unroll
            for (int i = 0; i < 4; ++i)
                af[i] = *(const f16x8*)(sA + ch * 1024 + (wm + i * 16 + l15) * 8);
#pragma unroll
            for (int j = 0; j < 4; ++j)
                bf[j] = *(const f16x8*)(sB + ch * 1024 + (wn + j * 16 + l15) * 8);
#pragma unroll
            for (int i = 0; i < 4; ++i)
#pragma unroll
                for (int j = 0; j < 4; ++j)
                    acc[i][j] = __builtin_amdgcn_mfma_f32_16x16x32_f16(
                        af[i], bf[j], acc[i][j], 0, 0, 0);
        }
        __syncthreads();
    }

    // epilogue: C/D col=lane&15, row=(lane>>4)*4+reg
#pragma unroll
    for (int i = 0; i < 4; ++i)
#pragma unroll
        for (int j = 0; j < 4; ++j) {
            const int col = n0 + wn + j * 16 + l15;
            const float bv = bias[col];
            const int rbase = m0 + wm + i * 16 + lg * 4;
            if (OUTMODE == 1) {
                _Float16* C = (_Float16*)Cout;
#pragma unroll
                for (int r = 0; r < 4; ++r) {
                    float v = acc[i][j][r] + bv;
                    float uu = v * (0.7978845608028654f + 0.0356774081363001f * v * v);
                    float e = __builtin_amdgcn_exp2f(uu * 2.8853900817779268f);
                    float rc = __builtin_amdgcn_rcpf(e + 1.0f);
                    C[(size_t)(rbase + r) * N + col] = (_Float16)(v * (1.0f - rc));
                }
            } else {
                float* C = (float*)Cout;
#pragma unroll
                for (int r = 0; r < 4; ++r)
                    C[(size_t)(rbase + r) * N + col] = acc[i][j][r] + bv;
            }
        }
}

extern "C" void kernel_launch(void* const* d_in, const int* in_sizes, int n_in,
                              void* d_out, int out_size, void* d_ws, size_t ws_size,
                              hipStream_t stream) {
    const float* x   = (const float*)d_in[0];
    const float* c0a = (const float*)d_in[1];
    const float* c0b = (const float*)d_in[2];
    const float* c0c = (const float*)d_in[3];
    const float* b0  = (const float*)d_in[4];
    const float* c1a = (const float*)d_in[5];
    const float* c1b = (const float*)d_in[6];
    const float* c1c = (const float*)d_in[7];
    const float* b1  = (const float*)d_in[8];
    float* out = (float*)d_out;

    char* ws = (char*)d_ws;
    _Float16* xh  = (_Float16*)(ws);                          // 16 MB
    _Float16* W0t = (_Float16*)(ws + (size_t)(16u << 20));    //  8 MB
    _Float16* W1t = (_Float16*)(ws + (size_t)(24u << 20));    //  8 MB
    _Float16* h   = (_Float16*)(ws + (size_t)(32u << 20));    // 64 MB

    // 1) fused prep: cast + both weight builds (1408 blocks)
    prep_kernel<<<dim3(1408), dim3(256), 0, stream>>>(
        x, xh, c0a, c0b, c0c, W0t, c1a, c1b, c1c, W1t);
    // 2) h = gelu(x @ W0 + b0)   M=8192 N=4096 K=1024   (2048 blocks, 8/CU)
    gemm16<1><<<dim3(64, 32), dim3(256), 0, stream>>>(
        xh, W0t, b0, (void*)h, 8192, 4096, 1024);
    // 3) out = h @ W1 + b1       M=8192 N=1024 K=4096   (512 blocks, 2/CU)
    gemm16<0><<<dim3(64, 8), dim3(256), 0, stream>>>(
        h, W1t, b1, (void*)out, 8192, 1024, 4096);
}

// Round 8
// 334.049 us; speedup vs baseline: 1.1962x; 1.1962x over previous
//
#include <hip/hip_runtime.h>
#include <math.h>

typedef _Float16 f16x8 __attribute__((ext_vector_type(8)));
typedef _Float16 f16x4 __attribute__((ext_vector_type(4)));
typedef float f32x16 __attribute__((ext_vector_type(16)));

__device__ __forceinline__ void async_copy16(const void* g, void* l) {
    __builtin_amdgcn_global_load_lds(
        (const __attribute__((address_space(1))) void*)g,
        (__attribute__((address_space(3))) void*)l, 16, 0, 0);
}

template <int N> __device__ __forceinline__ void vmcnt_wait() {
    if constexpr (N == 8)      asm volatile("s_waitcnt vmcnt(8)" ::: "memory");
    else if constexpr (N == 6) asm volatile("s_waitcnt vmcnt(6)" ::: "memory");
    else if constexpr (N == 4) asm volatile("s_waitcnt vmcnt(4)" ::: "memory");
    else if constexpr (N == 3) asm volatile("s_waitcnt vmcnt(3)" ::: "memory");
    else                       asm volatile("s_waitcnt vmcnt(0)" ::: "memory");
}

constexpr int ilog2(int x) { return x == 1 ? 0 : 1 + ilog2(x / 2); }

// ---------------- fused prep (R0 ORIGINAL, verbatim - part of the 306us config) ----------------
__global__ __launch_bounds__(256) void prep_kernel(
    const float* __restrict__ x, _Float16* __restrict__ xh,
    const float* __restrict__ c0a, const float* __restrict__ c0b,
    const float* __restrict__ c0c, _Float16* __restrict__ W0t,
    const float* __restrict__ c1a, const float* __restrict__ c1b,
    const float* __restrict__ c1c, _Float16* __restrict__ W1t) {
    __shared__ float G[16384];
    const int b = blockIdx.x, t = threadIdx.x;
    if (b < 1024) {
        const float4* in4 = (const float4*)x;
        f16x4* out4 = (f16x4*)xh;
        const int base = b * 2048 + t;
#pragma unroll
        for (int u = 0; u < 8; ++u) {
            float4 v = in4[base + u * 256];
            f16x4 o;
            o[0] = (_Float16)v.x; o[1] = (_Float16)v.y;
            o[2] = (_Float16)v.z; o[3] = (_Float16)v.w;
            out4[base + u * 256] = o;
        }
    } else if (b < 1280) {
        const int o = (b - 1024) >> 4, p = (b - 1024) & 15;
        // G[q16][r8][j16][k8] = sum_s c0b[r,j,p,s]*c0c[s,k,q]
#pragma unroll
        for (int n = 0; n < 64; ++n) {
            int idx = t + 256 * n;
            int k = idx & 7, j = (idx >> 3) & 15, r = (idx >> 7) & 7, q = idx >> 10;
            float s = 0.f;
#pragma unroll
            for (int ss = 0; ss < 8; ++ss)
                s += c0b[((r * 16 + j) * 16 + p) * 8 + ss] * c0c[(ss * 8 + k) * 16 + q];
            G[idx] = s;
        }
        __syncthreads();
        const int i = t >> 5, j = (t >> 1) & 15, kq = t & 1;
        float a[8];
#pragma unroll
        for (int r = 0; r < 8; ++r) a[r] = c0a[(i * 16 + o) * 8 + r];
        const float4* G4 = (const float4*)G;
#pragma unroll
        for (int q = 0; q < 16; ++q) {
            float4 acc = {0.f, 0.f, 0.f, 0.f};
#pragma unroll
            for (int r = 0; r < 8; ++r) {
                float4 g = G4[q * 256 + r * 32 + j * 2 + kq];
                acc.x += a[r] * g.x; acc.y += a[r] * g.y;
                acc.z += a[r] * g.z; acc.w += a[r] * g.w;
            }
            f16x4 h4;
            h4[0] = (_Float16)acc.x; h4[1] = (_Float16)acc.y;
            h4[2] = (_Float16)acc.z; h4[3] = (_Float16)acc.w;
            *(f16x4*)(W0t + (size_t)((o * 16 + p) * 16 + q) * 1024 + t * 4) = h4;
        }
    } else {
        const int o = (b - 1280) >> 4, p = (b - 1280) & 15;
        // G[q8][r8][j16][k16] = sum_s c1b[r,j,p,s]*c1c[s,k,q]
#pragma unroll
        for (int n = 0; n < 64; ++n) {
            int idx = t + 256 * n;
            int k = idx & 15, j = (idx >> 4) & 15, r = (idx >> 8) & 7, q = idx >> 11;
            float s = 0.f;
#pragma unroll
            for (int ss = 0; ss < 8; ++ss)
                s += c1b[((r * 16 + j) * 16 + p) * 8 + ss] * c1c[(ss * 16 + k) * 8 + q];
            G[idx] = s;
        }
        __syncthreads();
        const int ig = t >> 6, j = (t >> 2) & 15, kq = t & 3;
        float a[4][8];
#pragma unroll
        for (int ii = 0; ii < 4; ++ii)
#pragma unroll
            for (int r = 0; r < 8; ++r) a[ii][r] = c1a[((ig * 4 + ii) * 8 + o) * 8 + r];
        const float4* G4 = (const float4*)G;
#pragma unroll
        for (int q = 0; q < 8; ++q) {
            float4 acc[4] = {{0,0,0,0},{0,0,0,0},{0,0,0,0},{0,0,0,0}};
#pragma unroll
            for (int r = 0; r < 8; ++r) {
                float4 g = G4[q * 512 + r * 64 + j * 4 + kq];
#pragma unroll
                for (int ii = 0; ii < 4; ++ii) {
                    acc[ii].x += a[ii][r] * g.x; acc[ii].y += a[ii][r] * g.y;
                    acc[ii].z += a[ii][r] * g.z; acc[ii].w += a[ii][r] * g.w;
                }
            }
            const size_t rowbase = (size_t)((o * 16 + p) * 8 + q) * 4096;
#pragma unroll
            for (int ii = 0; ii < 4; ++ii) {
                f16x4 h4;
                h4[0] = (_Float16)acc[ii].x; h4[1] = (_Float16)acc[ii].y;
                h4[2] = (_Float16)acc[ii].z; h4[3] = (_Float16)acc[ii].w;
                *(f16x4*)(W1t + rowbase + (ig * 4 + ii) * 256 + j * 16 + kq * 4) = h4;
            }
        }
    }
}

// -------- R0 ORIGINAL GEMM (verbatim): 128x128, BK=64, 32x32x16, XOR-swizzled LDS --------
// Used for G2 only this round (hidden-champion measurement).
template <int OUTMODE>
__global__ __launch_bounds__(256) void gemm32_kernel(
    const _Float16* __restrict__ A, const _Float16* __restrict__ Bt,
    const float* __restrict__ bias, void* __restrict__ Cout,
    int M, int N, int K) {
    constexpr int BK = 64;
    __shared__ alignas(16) _Float16 sA[128 * BK];
    __shared__ alignas(16) _Float16 sB[128 * BK];

    const int t = threadIdx.x, lane = t & 63, w = t >> 6;
    const int m0 = blockIdx.x * 128, n0 = blockIdx.y * 128;
    const int wm = (w & 1) * 64, wn = (w >> 1) * 64;
    const int l31 = lane & 31, lh = lane >> 5;

    f32x16 acc[2][2] = {};

    const int s0 = w * 256 + lane;
    const int row0 = s0 >> 3;
    const int cslot = s0 & 7;
    const int kofs = (cslot ^ (row0 & 7)) * 8;
    const _Float16* gA = A + (size_t)(m0 + row0) * K + kofs;
    const _Float16* gB = Bt + (size_t)(n0 + row0) * K + kofs;
    _Float16* lA = sA + s0 * 8;
    _Float16* lB = sB + s0 * 8;
    const size_t rs = (size_t)8 * K;

    for (int k0 = 0; k0 < K; k0 += BK) {
#pragma unroll
        for (int m = 0; m < 4; ++m) {
            async_copy16(gA + k0 + m * rs, lA + m * 512);
            async_copy16(gB + k0 + m * rs, lB + m * 512);
        }
        __syncthreads();
#pragma unroll
        for (int kk = 0; kk < 4; ++kk) {
            f16x8 af[2], bf[2];
            const int c = kk * 2 + lh;
            const int sl = (c ^ (l31 & 7)) * 8;
#pragma unroll
            for (int i = 0; i < 2; ++i) {
                af[i] = *(const f16x8*)(sA + (wm + i * 32 + l31) * BK + sl);
                bf[i] = *(const f16x8*)(sB + (wn + i * 32 + l31) * BK + sl);
            }
#pragma unroll
            for (int i = 0; i < 2; ++i)
#pragma unroll
                for (int j = 0; j < 2; ++j)
                    acc[i][j] = __builtin_amdgcn_mfma_f32_32x32x16_f16(af[i], bf[j], acc[i][j], 0, 0, 0);
        }
        __syncthreads();
    }

#pragma unroll
    for (int i = 0; i < 2; ++i)
#pragma unroll
        for (int j = 0; j < 2; ++j) {
            const int col = n0 + wn + j * 32 + l31;
            const float bv = bias[col];
            const int rbase = m0 + wm + i * 32 + 4 * lh;
            if (OUTMODE == 1) {
                _Float16* C = (_Float16*)Cout;
#pragma unroll
                for (int r = 0; r < 16; ++r) {
                    int row = rbase + (r & 3) + 8 * (r >> 2);
                    float v = acc[i][j][r] + bv;
                    float uu = v * (0.7978845608028654f + 0.0356774081363001f * v * v);
                    float e = __builtin_amdgcn_exp2f(uu * 2.8853900817779268f);
                    float rc = __builtin_amdgcn_rcpf(e + 1.0f);
                    C[(size_t)row * N + col] = (_Float16)(v * (1.0f - rc));
                }
            } else {
                float* C = (float*)Cout;
#pragma unroll
                for (int r = 0; r < 16; ++r) {
                    int row = rbase + (r & 3) + 8 * (r >> 2);
                    C[(size_t)row * N + col] = acc[i][j][r] + bv;
                }
            }
        }
}

// ------- R6 gemm_pipe (verbatim, passed R6): BK=64 tiles, 2 phases/tile, counted vmcnt -------
template <int OUTMODE, int BM, int BN>
__global__ __launch_bounds__(512, 2) void gemm_pipe(
    const _Float16* __restrict__ A, const _Float16* __restrict__ Bt,
    const float* __restrict__ bias, void* __restrict__ Cout,
    int M, int N, int K) {
    constexpr int WM = BM / 2, WN = BN / 4;
    constexpr int MF = WM / 32, NF = WN / 32;
    constexpr int LAH = BM / 128;
    constexpr int LBH = BN / 128;
    constexpr int LPS = LAH + LBH;
    constexpr int BUFE = (BM + BN) * 64;
    constexpr int L2BM = ilog2(BM);

    __shared__ alignas(16) _Float16 lds[2 * BUFE];

    const int t = threadIdx.x, lane = t & 63, w = t >> 6;
    const int m0 = blockIdx.x * BM, n0 = blockIdx.y * BN;
    const int wm = (w & 1) * WM, wn = (w >> 1) * WN;
    const int l31 = lane & 31, lh = lane >> 5;
    const int NS = K >> 6;

    f32x16 acc[MF][NF] = {};

    const _Float16* gA = A + (size_t)(m0 + (t & (BM - 1))) * K + ((t >> L2BM) * 8);
    const _Float16* gB = Bt + (size_t)(n0 + (t & 255)) * K + ((t >> 8) * 8);

    auto stage_half = [&](int tile, int h) {
        const int buf = tile & 1;
        const int k0 = tile * 64 + h * 32;
        _Float16* dA = lds + buf * BUFE + h * (BM * 32) + t * 8;
#pragma unroll
        for (int u = 0; u < LAH; ++u)
            async_copy16(gA + k0 + u * (4096 / BM), dA + u * 4096);
        _Float16* dB = lds + buf * BUFE + BM * 64 + h * (BN * 32) + t * 8;
#pragma unroll
        for (int u = 0; u < LBH; ++u)
            async_copy16(gB + k0 + u * (4096 / BN), dB + u * 4096);
    };

    auto read_frags = [&](int buf, int p, f16x8 af[MF][2], f16x8 bf[NF][2]) {
        const _Float16* sa = lds + buf * BUFE;
        const _Float16* sb = sa + BM * 64;
#pragma unroll
        for (int q = 0; q < 2; ++q) {
            const int ch = 4 * p + 2 * q + lh;
#pragma unroll
            for (int i = 0; i < MF; ++i)
                af[i][q] = *(const f16x8*)(sa + ch * (BM * 8) + (wm + i * 32 + l31) * 8);
#pragma unroll
            for (int j = 0; j < NF; ++j)
                bf[j][q] = *(const f16x8*)(sb + ch * (BN * 8) + (wn + j * 32 + l31) * 8);
        }
    };
    auto do_mfma = [&](f16x8 af[MF][2], f16x8 bf[NF][2]) {
        __builtin_amdgcn_s_setprio(1);
#pragma unroll
        for (int q = 0; q < 2; ++q)
#pragma unroll
            for (int i = 0; i < MF; ++i)
#pragma unroll
                for (int j = 0; j < NF; ++j)
                    acc[i][j] = __builtin_amdgcn_mfma_f32_32x32x16_f16(
                        af[i][q], bf[j][q], acc[i][j], 0, 0, 0);
        __builtin_amdgcn_s_setprio(0);
    };

    stage_half(0, 0);
    stage_half(0, 1);
    vmcnt_wait<LPS>();
    __builtin_amdgcn_s_barrier();

    for (int tl = 0; tl < NS; ++tl) {
#pragma unroll
        for (int p = 0; p < 2; ++p) {
            f16x8 af[MF][2], bf[NF][2];
            read_frags(tl & 1, p, af, bf);
            if (tl + 1 < NS) stage_half(tl + 1, p);
            if (tl + 1 < NS) {
                vmcnt_wait<LPS>();
                __builtin_amdgcn_s_barrier();
            } else if (p == 0) {
                vmcnt_wait<0>();
                __builtin_amdgcn_s_barrier();
            }
            do_mfma(af, bf);
        }
    }

#pragma unroll
    for (int i = 0; i < MF; ++i)
#pragma unroll
        for (int j = 0; j < NF; ++j) {
            const int col = n0 + wn + j * 32 + l31;
            const float bv = bias[col];
            const int rbase = m0 + wm + i * 32 + 4 * lh;
            if (OUTMODE == 1) {
                _Float16* C = (_Float16*)Cout;
#pragma unroll
                for (int rr = 0; rr < 16; ++rr) {
                    int row = rbase + (rr & 3) + 8 * (rr >> 2);
                    float v = acc[i][j][rr] + bv;
                    float uu = v * (0.7978845608028654f + 0.0356774081363001f * v * v);
                    float e = __builtin_amdgcn_exp2f(uu * 2.8853900817779268f);
                    float rc = __builtin_amdgcn_rcpf(e + 1.0f);
                    C[(size_t)row * N + col] = (_Float16)(v * (1.0f - rc));
                }
            } else {
                float* C = (float*)Cout;
#pragma unroll
                for (int rr = 0; rr < 16; ++rr) {
                    int row = rbase + (rr & 3) + 8 * (rr >> 2);
                    C[(size_t)row * N + col] = acc[i][j][rr] + bv;
                }
            }
        }
}

extern "C" void kernel_launch(void* const* d_in, const int* in_sizes, int n_in,
                              void* d_out, int out_size, void* d_ws, size_t ws_size,
                              hipStream_t stream) {
    const float* x   = (const float*)d_in[0];
    const float* c0a = (const float*)d_in[1];
    const float* c0b = (const float*)d_in[2];
    const float* c0c = (const float*)d_in[3];
    const float* b0  = (const float*)d_in[4];
    const float* c1a = (const float*)d_in[5];
    const float* c1b = (const float*)d_in[6];
    const float* c1c = (const float*)d_in[7];
    const float* b1  = (const float*)d_in[8];
    float* out = (float*)d_out;

    char* ws = (char*)d_ws;
    _Float16* xh  = (_Float16*)(ws);                          // 16 MB
    _Float16* W0t = (_Float16*)(ws + (size_t)(16u << 20));    //  8 MB
    _Float16* W1t = (_Float16*)(ws + (size_t)(24u << 20));    //  8 MB
    _Float16* h   = (_Float16*)(ws + (size_t)(32u << 20));    // 64 MB

    // 1) fused prep (R0 original): cast + both weight builds
    prep_kernel<<<dim3(1408), dim3(256), 0, stream>>>(
        x, xh, c0a, c0b, c0c, W0t, c1a, c1b, c1c, W1t);
    // 2) h = gelu(x @ W0 + b0)   M=8192 N=4096 K=1024   (R6 gemm_pipe 256x256)
    gemm_pipe<1, 256, 256><<<dim3(32, 16), dim3(512), 0, stream>>>(
        xh, W0t, b0, (void*)h, 8192, 4096, 1024);
    // 3) out = h @ W1 + b1       M=8192 N=1024 K=4096   (R0 gemm32, 512 blocks)
    gemm32_kernel<0><<<dim3(64, 8), dim3(256), 0, stream>>>(
        h, W1t, b1, (void*)out, 8192, 1024, 4096);
}

// Round 9
// 283.235 us; speedup vs baseline: 1.4108x; 1.1794x over previous
//
#include <hip/hip_runtime.h>
#include <math.h>

typedef _Float16 f16x8 __attribute__((ext_vector_type(8)));
typedef _Float16 f16x4 __attribute__((ext_vector_type(4)));
typedef float f32x16 __attribute__((ext_vector_type(16)));

__device__ __forceinline__ void async_copy16(const void* g, void* l) {
    __builtin_amdgcn_global_load_lds(
        (const __attribute__((address_space(1))) void*)g,
        (__attribute__((address_space(3))) void*)l, 16, 0, 0);
}

// ---------------- fused prep (R6-verified restructured G-build) ----------------
__global__ __launch_bounds__(256) void prep_kernel(
    const float* __restrict__ x, _Float16* __restrict__ xh,
    const float* __restrict__ c0a, const float* __restrict__ c0b,
    const float* __restrict__ c0c, _Float16* __restrict__ W0t,
    const float* __restrict__ c1a, const float* __restrict__ c1b,
    const float* __restrict__ c1c, _Float16* __restrict__ W1t) {
    __shared__ float G[16384];
    const int b = blockIdx.x, t = threadIdx.x;
    if (b < 1024) {
        const float4* in4 = (const float4*)x;
        f16x4* out4 = (f16x4*)xh;
        const int base = b * 2048 + t;
#pragma unroll
        for (int u = 0; u < 8; ++u) {
            float4 v = in4[base + u * 256];
            f16x4 o;
            o[0] = (_Float16)v.x; o[1] = (_Float16)v.y;
            o[2] = (_Float16)v.z; o[3] = (_Float16)v.w;
            out4[base + u * 256] = o;
        }
    } else if (b < 1280) {
        const int o = (b - 1024) >> 4, p = (b - 1024) & 15;
        // G[q16][r8][j16][k8] = sum_ss c0b[r,j,p,ss]*c0c[ss,k,q]; idx=q*1024+rj*8+k
        {
            const int h = t >> 7, qk = t & 127, q = qk >> 3, k = qk & 7;
            float cr[8];
#pragma unroll
            for (int ss = 0; ss < 8; ++ss) cr[ss] = c0c[(ss * 8 + k) * 16 + q];
            for (int rj = h * 64; rj < h * 64 + 64; ++rj) {
                const float4* b4 = (const float4*)(c0b + (rj * 16 + p) * 8);
                float4 b0 = b4[0], b1 = b4[1];
                float s = b0.x * cr[0] + b0.y * cr[1] + b0.z * cr[2] + b0.w * cr[3]
                        + b1.x * cr[4] + b1.y * cr[5] + b1.z * cr[6] + b1.w * cr[7];
                G[q * 1024 + rj * 8 + k] = s;
            }
        }
        __syncthreads();
        const int i = t >> 5, j = (t >> 1) & 15, kq = t & 1;
        float a[8];
#pragma unroll
        for (int r = 0; r < 8; ++r) a[r] = c0a[(i * 16 + o) * 8 + r];
        const float4* G4 = (const float4*)G;
#pragma unroll
        for (int q = 0; q < 16; ++q) {
            float4 acc = {0.f, 0.f, 0.f, 0.f};
#pragma unroll
            for (int r = 0; r < 8; ++r) {
                float4 g = G4[q * 256 + r * 32 + j * 2 + kq];
                acc.x += a[r] * g.x; acc.y += a[r] * g.y;
                acc.z += a[r] * g.z; acc.w += a[r] * g.w;
            }
            f16x4 h4;
            h4[0] = (_Float16)acc.x; h4[1] = (_Float16)acc.y;
            h4[2] = (_Float16)acc.z; h4[3] = (_Float16)acc.w;
            *(f16x4*)(W0t + (size_t)((o * 16 + p) * 16 + q) * 1024 + t * 4) = h4;
        }
    } else {
        const int o = (b - 1280) >> 4, p = (b - 1280) & 15;
        // G[q8][r8][j16][k16] = sum_ss c1b[r,j,p,ss]*c1c[ss,k,q]; idx=q*2048+rj*16+k
        {
            const int h = t >> 7, qk = t & 127, q = qk >> 4, k = qk & 15;
            float cr[8];
#pragma unroll
            for (int ss = 0; ss < 8; ++ss) cr[ss] = c1c[(ss * 16 + k) * 8 + q];
            for (int rj = h * 64; rj < h * 64 + 64; ++rj) {
                const float4* b4 = (const float4*)(c1b + (rj * 16 + p) * 8);
                float4 b0 = b4[0], b1 = b4[1];
                float s = b0.x * cr[0] + b0.y * cr[1] + b0.z * cr[2] + b0.w * cr[3]
                        + b1.x * cr[4] + b1.y * cr[5] + b1.z * cr[6] + b1.w * cr[7];
                G[q * 2048 + rj * 16 + k] = s;
            }
        }
        __syncthreads();
        const int ig = t >> 6, j = (t >> 2) & 15, kq = t & 3;
        float a[4][8];
#pragma unroll
        for (int ii = 0; ii < 4; ++ii)
#pragma unroll
            for (int r = 0; r < 8; ++r) a[ii][r] = c1a[((ig * 4 + ii) * 8 + o) * 8 + r];
        const float4* G4 = (const float4*)G;
#pragma unroll
        for (int q = 0; q < 8; ++q) {
            float4 acc[4] = {{0,0,0,0},{0,0,0,0},{0,0,0,0},{0,0,0,0}};
#pragma unroll
            for (int r = 0; r < 8; ++r) {
                float4 g = G4[q * 512 + r * 64 + j * 4 + kq];
#pragma unroll
                for (int ii = 0; ii < 4; ++ii) {
                    acc[ii].x += a[ii][r] * g.x; acc[ii].y += a[ii][r] * g.y;
                    acc[ii].z += a[ii][r] * g.z; acc[ii].w += a[ii][r] * g.w;
                }
            }
            const size_t rowbase = (size_t)((o * 16 + p) * 8 + q) * 4096;
#pragma unroll
            for (int ii = 0; ii < 4; ++ii) {
                f16x4 h4;
                h4[0] = (_Float16)acc[ii].x; h4[1] = (_Float16)acc[ii].y;
                h4[2] = (_Float16)acc[ii].z; h4[3] = (_Float16)acc[ii].w;
                *(f16x4*)(W1t + rowbase + (ig * 4 + ii) * 256 + j * 16 + kq * 4) = h4;
            }
        }
    }
}

// -------- CHAMPION GEMM (R0 verbatim, ledger-measured 96us for G1): 128x128, BK=64,
// 32x32x16, XOR-swizzled row-major LDS, classic 2-barrier, 32KB LDS -> 5 blk/CU --------
template <int OUTMODE>
__global__ __launch_bounds__(256) void gemm32_kernel(
    const _Float16* __restrict__ A, const _Float16* __restrict__ Bt,
    const float* __restrict__ bias, void* __restrict__ Cout,
    int M, int N, int K) {
    constexpr int BK = 64;
    __shared__ alignas(16) _Float16 sA[128 * BK];
    __shared__ alignas(16) _Float16 sB[128 * BK];

    const int t = threadIdx.x, lane = t & 63, w = t >> 6;
    const int m0 = blockIdx.x * 128, n0 = blockIdx.y * 128;
    const int wm = (w & 1) * 64, wn = (w >> 1) * 64;
    const int l31 = lane & 31, lh = lane >> 5;

    f32x16 acc[2][2] = {};

    const int s0 = w * 256 + lane;
    const int row0 = s0 >> 3;
    const int cslot = s0 & 7;
    const int kofs = (cslot ^ (row0 & 7)) * 8;
    const _Float16* gA = A + (size_t)(m0 + row0) * K + kofs;
    const _Float16* gB = Bt + (size_t)(n0 + row0) * K + kofs;
    _Float16* lA = sA + s0 * 8;
    _Float16* lB = sB + s0 * 8;
    const size_t rs = (size_t)8 * K;

    for (int k0 = 0; k0 < K; k0 += BK) {
#pragma unroll
        for (int m = 0; m < 4; ++m) {
            async_copy16(gA + k0 + m * rs, lA + m * 512);
            async_copy16(gB + k0 + m * rs, lB + m * 512);
        }
        __syncthreads();
#pragma unroll
        for (int kk = 0; kk < 4; ++kk) {
            f16x8 af[2], bf[2];
            const int c = kk * 2 + lh;
            const int sl = (c ^ (l31 & 7)) * 8;
#pragma unroll
            for (int i = 0; i < 2; ++i) {
                af[i] = *(const f16x8*)(sA + (wm + i * 32 + l31) * BK + sl);
                bf[i] = *(const f16x8*)(sB + (wn + i * 32 + l31) * BK + sl);
            }
#pragma unroll
            for (int i = 0; i < 2; ++i)
#pragma unroll
                for (int j = 0; j < 2; ++j)
                    acc[i][j] = __builtin_amdgcn_mfma_f32_32x32x16_f16(af[i], bf[j], acc[i][j], 0, 0, 0);
        }
        __syncthreads();
    }

#pragma unroll
    for (int i = 0; i < 2; ++i)
#pragma unroll
        for (int j = 0; j < 2; ++j) {
            const int col = n0 + wn + j * 32 + l31;
            const float bv = bias[col];
            const int rbase = m0 + wm + i * 32 + 4 * lh;
            if (OUTMODE == 1) {
                _Float16* C = (_Float16*)Cout;
#pragma unroll
                for (int r = 0; r < 16; ++r) {
                    int row = rbase + (r & 3) + 8 * (r >> 2);
                    float v = acc[i][j][r] + bv;
                    float uu = v * (0.7978845608028654f + 0.0356774081363001f * v * v);
                    float e = __builtin_amdgcn_exp2f(uu * 2.8853900817779268f);
                    float rc = __builtin_amdgcn_rcpf(e + 1.0f);
                    C[(size_t)row * N + col] = (_Float16)(v * (1.0f - rc));
                }
            } else {
                float* C = (float*)Cout;
#pragma unroll
                for (int r = 0; r < 16; ++r) {
                    int row = rbase + (r & 3) + 8 * (r >> 2);
                    C[(size_t)row * N + col] = acc[i][j][r] + bv;
                }
            }
        }
}

// -------- Split-K x2 variant of the champion (G2 TLP fix: 1024 blocks = 4 blk/CU) --------
// z=0 computes K[0,K/2) -> p0 (=out, fp32, no bias); z=1 computes K[K/2,K) -> p1.
// Row stride stays full K. Epilogue: raw fp32 partial store.
__global__ __launch_bounds__(256) void gemm32_splitk(
    const _Float16* __restrict__ A, const _Float16* __restrict__ Bt,
    float* __restrict__ p0, float* __restrict__ p1,
    int M, int N, int K) {
    constexpr int BK = 64;
    __shared__ alignas(16) _Float16 sA[128 * BK];
    __shared__ alignas(16) _Float16 sB[128 * BK];

    const int t = threadIdx.x, lane = t & 63, w = t >> 6;
    const int m0 = blockIdx.x * 128, n0 = blockIdx.y * 128;
    const int wm = (w & 1) * 64, wn = (w >> 1) * 64;
    const int l31 = lane & 31, lh = lane >> 5;

    f32x16 acc[2][2] = {};

    const int s0 = w * 256 + lane;
    const int row0 = s0 >> 3;
    const int cslot = s0 & 7;
    const int kofs = (cslot ^ (row0 & 7)) * 8;
    const _Float16* gA = A + (size_t)(m0 + row0) * K + kofs;
    const _Float16* gB = Bt + (size_t)(n0 + row0) * K + kofs;
    _Float16* lA = sA + s0 * 8;
    _Float16* lB = sB + s0 * 8;
    const size_t rs = (size_t)8 * K;

    const int kbase = blockIdx.z * (K >> 1);
    const int kend = kbase + (K >> 1);
    for (int k0 = kbase; k0 < kend; k0 += BK) {
#pragma unroll
        for (int m = 0; m < 4; ++m) {
            async_copy16(gA + k0 + m * rs, lA + m * 512);
            async_copy16(gB + k0 + m * rs, lB + m * 512);
        }
        __syncthreads();
#pragma unroll
        for (int kk = 0; kk < 4; ++kk) {
            f16x8 af[2], bf[2];
            const int c = kk * 2 + lh;
            const int sl = (c ^ (l31 & 7)) * 8;
#pragma unroll
            for (int i = 0; i < 2; ++i) {
                af[i] = *(const f16x8*)(sA + (wm + i * 32 + l31) * BK + sl);
                bf[i] = *(const f16x8*)(sB + (wn + i * 32 + l31) * BK + sl);
            }
#pragma unroll
            for (int i = 0; i < 2; ++i)
#pragma unroll
                for (int j = 0; j < 2; ++j)
                    acc[i][j] = __builtin_amdgcn_mfma_f32_32x32x16_f16(af[i], bf[j], acc[i][j], 0, 0, 0);
        }
        __syncthreads();
    }

    float* C = blockIdx.z ? p1 : p0;
#pragma unroll
    for (int i = 0; i < 2; ++i)
#pragma unroll
        for (int j = 0; j < 2; ++j) {
            const int col = n0 + wn + j * 32 + l31;
            const int rbase = m0 + wm + i * 32 + 4 * lh;
#pragma unroll
            for (int r = 0; r < 16; ++r) {
                int row = rbase + (r & 3) + 8 * (r >> 2);
                C[(size_t)row * N + col] = acc[i][j][r];
            }
        }
}

// out[i] = out[i](=p0) + p1[i] + bias[col]; float4 grid-stride (96MB traffic)
__global__ __launch_bounds__(256) void reduce_bias(
    const float* __restrict__ p1, const float* __restrict__ bias,
    float* __restrict__ out, int total4, int N) {
    const float4* q4 = (const float4*)p1;
    float4* o4 = (float4*)out;
    for (int i = blockIdx.x * 256 + threadIdx.x; i < total4; i += gridDim.x * 256) {
        float4 o = o4[i], q = q4[i];
        const int col = (i << 2) & (N - 1);
        const float4 b = *(const float4*)(bias + col);
        o.x += q.x + b.x; o.y += q.y + b.y;
        o.z += q.z + b.z; o.w += q.w + b.w;
        o4[i] = o;
    }
}

extern "C" void kernel_launch(void* const* d_in, const int* in_sizes, int n_in,
                              void* d_out, int out_size, void* d_ws, size_t ws_size,
                              hipStream_t stream) {
    const float* x   = (const float*)d_in[0];
    const float* c0a = (const float*)d_in[1];
    const float* c0b = (const float*)d_in[2];
    const float* c0c = (const float*)d_in[3];
    const float* b0  = (const float*)d_in[4];
    const float* c1a = (const float*)d_in[5];
    const float* c1b = (const float*)d_in[6];
    const float* c1c = (const float*)d_in[7];
    const float* b1  = (const float*)d_in[8];
    float* out = (float*)d_out;

    char* ws = (char*)d_ws;
    _Float16* xh  = (_Float16*)(ws);                          // 16 MB
    _Float16* W0t = (_Float16*)(ws + (size_t)(16u << 20));    //  8 MB
    _Float16* W1t = (_Float16*)(ws + (size_t)(24u << 20));    //  8 MB
    _Float16* h   = (_Float16*)(ws + (size_t)(32u << 20));    // 64 MB
    float*    p1  = (float*)   (ws + (size_t)(96u << 20));    // 32 MB (if ws allows)

    // 1) fused prep: cast + both weight builds (1408 blocks)
    prep_kernel<<<dim3(1408), dim3(256), 0, stream>>>(
        x, xh, c0a, c0b, c0c, W0t, c1a, c1b, c1c, W1t);
    // 2) h = gelu(x @ W0 + b0)   M=8192 N=4096 K=1024  (champion, 2048 blocks, 5/CU cap)
    gemm32_kernel<1><<<dim3(64, 32), dim3(256), 0, stream>>>(
        xh, W0t, b0, (void*)h, 8192, 4096, 1024);
    // 3) out = h @ W1 + b1       M=8192 N=1024 K=4096
    if (ws_size >= ((size_t)128u << 20)) {
        // split-K x2: 1024 blocks (4/CU); partials: z0->out, z1->p1; then reduce+bias
        gemm32_splitk<<<dim3(64, 8, 2), dim3(256), 0, stream>>>(
            h, W1t, out, p1, 8192, 1024, 4096);
        reduce_bias<<<dim3(2048), dim3(256), 0, stream>>>(
            p1, b1, out, (8192 * 1024) / 4, 1024);
    } else {
        // fallback: exact R0 G2 (512 blocks)
        gemm32_kernel<0><<<dim3(64, 8), dim3(256), 0, stream>>>(
            h, W1t, b1, (void*)out, 8192, 1024, 4096);
    }
}